// Round 5
// baseline (370.053 us; speedup 1.0000x reference)
//
#include <hip/hip_runtime.h>
#include <cstdint>
#include <cstddef>

typedef unsigned short u16;
typedef unsigned int u32;
typedef float f32x4 __attribute__((ext_vector_type(4)));
typedef short bf16x8 __attribute__((ext_vector_type(8)));

// Problem constants: B=4, N=S=1024, C=768, H=12, d=64
// ws layout (bytes):
//   X    @ 0         : 4096x768  bf16 (query cast)            6291456
//   Wqkv @ 6291456   : 2304x768  bf16 (Wq|Wk|Wv rows)         3538944
//   Wob  @ 9830400   : 768x768   bf16                         1179648
//   QKV  @ 11010048  : [3][4][12][1024][64] bf16             18874368
//   Vt   @ 29884416  : [4][12][64][1024] bf16                 6291456
//   Oa   @ 36175872  : [4096][768] bf16 (attn out, token-major) 6291456

#define GLOAD_LDS16(g, l)                                                        \
  __builtin_amdgcn_global_load_lds(                                              \
      (const __attribute__((address_space(1))) void*)(g),                        \
      (__attribute__((address_space(3))) void*)(l), 16, 0, 0)

__device__ __forceinline__ u16 f2bf(float f) {
  u32 u = __float_as_uint(f);
  u32 r = ((u >> 16) & 1u) + 0x7fffu;  // RNE
  return (u16)((u + r) >> 16);
}

__device__ __forceinline__ float redmax16(float v) {
  v = fmaxf(v, __shfl_xor(v, 8, 16));
  v = fmaxf(v, __shfl_xor(v, 4, 16));
  v = fmaxf(v, __shfl_xor(v, 2, 16));
  v = fmaxf(v, __shfl_xor(v, 1, 16));
  return v;
}
__device__ __forceinline__ float redsum16(float v) {
  v += __shfl_xor(v, 8, 16);
  v += __shfl_xor(v, 4, 16);
  v += __shfl_xor(v, 2, 16);
  v += __shfl_xor(v, 1, 16);
  return v;
}

// ---------------- cast all fp32 inputs to bf16 (flat ranges, 4 elems/thread) ---------
__global__ __launch_bounds__(256) void cast_all(
    const float* __restrict__ q, const float* __restrict__ wq, const float* __restrict__ wk,
    const float* __restrict__ wv, const float* __restrict__ wo,
    u16* __restrict__ X, u16* __restrict__ Wqkv, u16* __restrict__ Wob) {
  int id = blockIdx.x * 256 + threadIdx.x;  // quad index; grid covers exactly 1376256
  const float* src;
  u16* dst;
  if (id < 786432) {                     // query -> X
    src = q + (size_t)id * 4;       dst = X + (size_t)id * 4;
  } else if (id < 933888) {              // Wq -> Wqkv[0:768]
    int o = id - 786432;  src = wq + (size_t)o * 4; dst = Wqkv + (size_t)o * 4;
  } else if (id < 1081344) {             // Wk -> Wqkv[768:1536]
    int o = id - 933888;  src = wk + (size_t)o * 4; dst = Wqkv + 589824 + (size_t)o * 4;
  } else if (id < 1228800) {             // Wv -> Wqkv[1536:2304]
    int o = id - 1081344; src = wv + (size_t)o * 4; dst = Wqkv + 1179648 + (size_t)o * 4;
  } else {                               // Wo -> Wob
    int o = id - 1228800; src = wo + (size_t)o * 4; dst = Wob + (size_t)o * 4;
  }
  float4 v = *(const float4*)src;
  uint2 o2;
  o2.x = (u32)f2bf(v.x) | ((u32)f2bf(v.y) << 16);
  o2.y = (u32)f2bf(v.z) | ((u32)f2bf(v.w) << 16);
  *(uint2*)dst = o2;
}

// ---------------- 128x128 MFMA GEMM, C = A * B^T, A[M,K] bf16, Bm[N,K] bf16 ----------
// m97 structure: linear [128][64] LDS per tile, global_load_lds 16B staging.
// XOR-swizzle (col ^= (row&7)<<3 elems) applied as inverse-swizzled SOURCE +
// swizzled READ (linear gload_lds dest, rule #21). CONTROL: unchanged from R1.
// MODE 0: K=768, N=2304, scatter-store bf16 into QKV [t][b][h][n][64]
template <int MODE>
__global__ __launch_bounds__(256) void gemm_bt(
    const u16* __restrict__ A, const u16* __restrict__ Bm,
    u16* __restrict__ Cq, float* __restrict__ Cf, const float* __restrict__ bias) {
  constexpr int K = 768;
  __shared__ u16 As[128 * 64];
  __shared__ u16 Bs[128 * 64];
  const int tid = threadIdx.x;
  const int w = tid >> 6, lane = tid & 63, quad = lane >> 4, l16 = lane & 15;
  const int m0 = blockIdx.y * 128, n0 = blockIdx.x * 128;
  const int wm = (w >> 1) * 64, wn = (w & 1) * 64;
  const int xr = (l16 & 7) << 3;  // read-side XOR (row&7 == l16&7 for 16-aligned rows)

  f32x4 acc[4][4];
#pragma unroll
  for (int i = 0; i < 4; ++i)
#pragma unroll
    for (int j = 0; j < 4; ++j)
#pragma unroll
      for (int r = 0; r < 4; ++r) acc[i][j][r] = 0.f;

  for (int kt = 0; kt < K; kt += 64) {
#pragma unroll
    for (int t = 0; t < 4; ++t) {
      int id = (t * 4 + w) * 64 + lane;          // 0..1023: lane's 16B within tile
      int row = id >> 3;
      int scol = ((id & 7) ^ (row & 7)) << 3;    // inverse-swizzled source column
      GLOAD_LDS16(A + (size_t)(m0 + row) * K + kt + scol, As + (t * 4 + w) * 512);
      GLOAD_LDS16(Bm + (size_t)(n0 + row) * K + kt + scol, Bs + (t * 4 + w) * 512);
    }
    __syncthreads();
#pragma unroll
    for (int kk = 0; kk < 2; ++kk) {
      bf16x8 af[4], bfr[4];
#pragma unroll
      for (int mi = 0; mi < 4; ++mi)
        af[mi] = *(const bf16x8*)(As + (wm + mi * 16 + l16) * 64 + ((kk * 32 + quad * 8) ^ xr));
#pragma unroll
      for (int ni = 0; ni < 4; ++ni)
        bfr[ni] = *(const bf16x8*)(Bs + (wn + ni * 16 + l16) * 64 + ((kk * 32 + quad * 8) ^ xr));
#pragma unroll
      for (int mi = 0; mi < 4; ++mi)
#pragma unroll
        for (int ni = 0; ni < 4; ++ni)
          acc[mi][ni] = __builtin_amdgcn_mfma_f32_16x16x32_bf16(af[mi], bfr[ni], acc[mi][ni], 0, 0, 0);
    }
    __syncthreads();
  }

#pragma unroll
  for (int ni = 0; ni < 4; ++ni) {
    int cb = n0 + wn + ni * 16;  // 16-aligned; never straddles 768 or 64 boundaries
#pragma unroll
    for (int mi = 0; mi < 4; ++mi) {
#pragma unroll
      for (int r = 0; r < 4; ++r) {
        int m = m0 + wm + mi * 16 + quad * 4 + r;  // C/D row = quad*4+reg
        float v = acc[mi][ni][r];
        if (MODE == 0) {
          int t = cb / 768;
          int c = cb - t * 768;
          int h = c >> 6, dd = (c & 63) + l16;     // C/D col = lane&15
          int b = m >> 10, ntok = m & 1023;
          Cq[(size_t)((t * 4 + b) * 12 + h) * 65536 + (size_t)ntok * 64 + dd] = f2bf(v);
        } else {
          int n = cb + l16;
          Cf[(size_t)m * 768 + n] = v + bias[n];
        }
      }
    }
  }
}

// ---------------- 64x128 GEMM for the output projection (occupancy fix) -------------
// M=4096, N=768, K=768. grid (6, 64) = 384 blocks (1.5/CU vs 0.75 at 128x128).
// Same m97 staging + swizzle discipline. Wave owns 32x64; acc[2][4].
__global__ __launch_bounds__(256) void gemm_bt64(
    const u16* __restrict__ A, const u16* __restrict__ Bm,
    float* __restrict__ Cf, const float* __restrict__ bias) {
  constexpr int K = 768;
  __shared__ u16 As[64 * 64];    // 8 KB
  __shared__ u16 Bs[128 * 64];   // 16 KB
  const int tid = threadIdx.x;
  const int w = tid >> 6, lane = tid & 63, quad = lane >> 4, l16 = lane & 15;
  const int m0 = blockIdx.y * 64, n0 = blockIdx.x * 128;
  const int wm = (w >> 1) * 32, wn = (w & 1) * 64;
  const int xr = (l16 & 7) << 3;

  f32x4 acc[2][4];
#pragma unroll
  for (int i = 0; i < 2; ++i)
#pragma unroll
    for (int j = 0; j < 4; ++j)
#pragma unroll
      for (int r = 0; r < 4; ++r) acc[i][j][r] = 0.f;

  for (int kt = 0; kt < K; kt += 64) {
#pragma unroll
    for (int t = 0; t < 4; ++t) {
      int id = (t * 4 + w) * 64 + lane;
      int row = id >> 3, scol = ((id & 7) ^ (row & 7)) << 3;
      GLOAD_LDS16(Bm + (size_t)(n0 + row) * K + kt + scol, Bs + (t * 4 + w) * 512);
      if (t < 2) {  // A tile: 8 chunks (rows 0..63)
        GLOAD_LDS16(A + (size_t)(m0 + row) * K + kt + scol, As + (t * 4 + w) * 512);
      }
    }
    __syncthreads();
#pragma unroll
    for (int kk = 0; kk < 2; ++kk) {
      bf16x8 af[2], bfr[4];
#pragma unroll
      for (int mi = 0; mi < 2; ++mi)
        af[mi] = *(const bf16x8*)(As + (wm + mi * 16 + l16) * 64 + ((kk * 32 + quad * 8) ^ xr));
#pragma unroll
      for (int ni = 0; ni < 4; ++ni)
        bfr[ni] = *(const bf16x8*)(Bs + (wn + ni * 16 + l16) * 64 + ((kk * 32 + quad * 8) ^ xr));
#pragma unroll
      for (int mi = 0; mi < 2; ++mi)
#pragma unroll
        for (int ni = 0; ni < 4; ++ni)
          acc[mi][ni] = __builtin_amdgcn_mfma_f32_16x16x32_bf16(af[mi], bfr[ni], acc[mi][ni], 0, 0, 0);
    }
    __syncthreads();
  }

#pragma unroll
  for (int ni = 0; ni < 4; ++ni) {
    int n = n0 + wn + ni * 16 + l16;
#pragma unroll
    for (int mi = 0; mi < 2; ++mi) {
#pragma unroll
      for (int r = 0; r < 4; ++r) {
        int m = m0 + wm + mi * 16 + quad * 4 + r;
        Cf[(size_t)m * 768 + n] = acc[mi][ni][r] + bias[n];
      }
    }
  }
}

// ---------------- transpose V head-tiles: [b][h][n][64] -> [b][h][64][n] ------------
__global__ __launch_bounds__(256) void transpose_v(const u16* __restrict__ QKV,
                                                   u16* __restrict__ Vt) {
  __shared__ u16 tsm[64 * 72];
  const int bh = blockIdx.y, n0 = blockIdx.x * 64;
  const u16* V = QKV + (size_t)(96 + bh) * 65536;  // t=2 slice
  const int tid = threadIdx.x;
  const int r = tid >> 2, ch = tid & 3;
  *(int4*)(tsm + r * 72 + ch * 16) = *(const int4*)(V + (size_t)(n0 + r) * 64 + ch * 16);
  *(int4*)(tsm + r * 72 + ch * 16 + 8) = *(const int4*)(V + (size_t)(n0 + r) * 64 + ch * 16 + 8);
  __syncthreads();
  const int dd = tid >> 2;
  alignas(16) u16 buf[16];
#pragma unroll
  for (int i = 0; i < 16; ++i) buf[i] = tsm[(ch * 16 + i) * 72 + dd];
  u16* dst = Vt + ((size_t)bh * 64 + dd) * 1024 + n0 + ch * 16;
  *(int4*)dst = *(int4*)buf;
  *(int4*)(dst + 8) = *((int4*)buf + 1);
}

// ---------------- fused attention: softmax(QK^T/8 + W) V, online softmax ------------
// grid (16 q-tiles of 64, 48 bh); 256 threads = 4 waves, 16 q-rows per wave.
// K/V double-buffered via global_load_lds prefetched one tile ahead; W bias
// prefetched one tile ahead into registers. LDS = 40960 B exactly -> 4 blocks/CU
// (Ps shrunk to stride-64 + XOR swizzle, same algebra as K-tile: row&7==l16&7).
__global__ __launch_bounds__(256, 4) void attn_kernel(
    const u16* __restrict__ QKV, const u16* __restrict__ Vt,
    const float* __restrict__ W, u16* __restrict__ Oa) {
  __shared__ u16 Ks2[2][64 * 64];  // [buf][s_local][dd], XOR-swizzled storage
  __shared__ u16 Vs2[2][64 * 64];  // [buf][dd][s_local], XOR-swizzled storage
  __shared__ u16 Ps[4][16 * 64];   // per-wave P tile [m][s_local], XOR-swizzled
  const int tid = threadIdx.x;
  const int w = tid >> 6, lane = tid & 63, quad = lane >> 4, l16 = lane & 15;
  const int bh = blockIdx.y, q0 = blockIdx.x * 64;
  const u16* Qh = QKV + (size_t)bh * 65536;
  const u16* Kh = QKV + (size_t)(48 + bh) * 65536;
  const u16* Vth = Vt + (size_t)bh * 65536;
  const float* Wp = W + (size_t)bh * 1048576 + (size_t)(q0 + w * 16 + quad * 4) * 1024 + l16;
  const int xr = (l16 & 7) << 3;

  // Q fragments for this wave's 16 rows (A-layout: m=lane&15, k=quad*8+j)
  bf16x8 aq0, aq1;
  {
    int qrow = q0 + w * 16 + l16;
    aq0 = *(const bf16x8*)(Qh + (size_t)qrow * 64 + quad * 8);
    aq1 = *(const bf16x8*)(Qh + (size_t)qrow * 64 + 32 + quad * 8);
  }

  // staging geometry: 8KB tile = 8 x 1KB chunks; chunk = c*4+w; lane covers 16B
  const int sid0 = (0 * 4 + w) * 64 + lane;
  const int sid1 = (1 * 4 + w) * 64 + lane;
  const int r0 = sid0 >> 3, sl0 = ((sid0 & 7) ^ (r0 & 7)) << 3;
  const int r1 = sid1 >> 3, sl1 = ((sid1 & 7) ^ (r1 & 7)) << 3;

  // prologue: stage tile 0 into buf 0; W tile 0 into regs
  GLOAD_LDS16(Kh + (size_t)r0 * 64 + sl0, &Ks2[0][(0 * 4 + w) * 512]);
  GLOAD_LDS16(Kh + (size_t)r1 * 64 + sl1, &Ks2[0][(1 * 4 + w) * 512]);
  GLOAD_LDS16(Vth + (size_t)r0 * 1024 + sl0, &Vs2[0][(0 * 4 + w) * 512]);
  GLOAD_LDS16(Vth + (size_t)r1 * 1024 + sl1, &Vs2[0][(1 * 4 + w) * 512]);
  float wc[4][4];
#pragma unroll
  for (int r = 0; r < 4; ++r)
#pragma unroll
    for (int j = 0; j < 4; ++j) wc[j][r] = Wp[(size_t)r * 1024 + j * 16];

  f32x4 o[4];
  float mrow[4], lrow[4];
#pragma unroll
  for (int j = 0; j < 4; ++j)
#pragma unroll
    for (int r = 0; r < 4; ++r) o[j][r] = 0.f;
#pragma unroll
  for (int r = 0; r < 4; ++r) { mrow[r] = -1e30f; lrow[r] = 0.f; }

  for (int st = 0; st < 16; ++st) {
    const int cur = st & 1;
    __syncthreads();  // drains staged tile(st); all waves done reading buf[cur^1]

    // prefetch tile st+1 into buf[cur^1]; skip on last iter (no dangling
    // in-flight LDS DMA at endpgm, no wasted HBM traffic)
    float wn[4][4];
    if (st < 15) {
      const int sn = (st + 1) * 64;
      GLOAD_LDS16(Kh + (size_t)(sn + r0) * 64 + sl0, &Ks2[cur ^ 1][(0 * 4 + w) * 512]);
      GLOAD_LDS16(Kh + (size_t)(sn + r1) * 64 + sl1, &Ks2[cur ^ 1][(1 * 4 + w) * 512]);
      GLOAD_LDS16(Vth + (size_t)r0 * 1024 + sn + sl0, &Vs2[cur ^ 1][(0 * 4 + w) * 512]);
      GLOAD_LDS16(Vth + (size_t)r1 * 1024 + sn + sl1, &Vs2[cur ^ 1][(1 * 4 + w) * 512]);
#pragma unroll
      for (int r = 0; r < 4; ++r)
#pragma unroll
        for (int j = 0; j < 4; ++j) wn[j][r] = Wp[(size_t)r * 1024 + sn + j * 16];
    }

    const u16* Kb = Ks2[cur];
    const u16* Vb = Vs2[cur];

    // scores: S[m=q-row][n=s-col]
    f32x4 sf[4];
#pragma unroll
    for (int j = 0; j < 4; ++j) {
#pragma unroll
      for (int r = 0; r < 4; ++r) sf[j][r] = 0.f;
      bf16x8 bk0 = *(const bf16x8*)(Kb + (j * 16 + l16) * 64 + ((quad * 8) ^ xr));
      bf16x8 bk1 = *(const bf16x8*)(Kb + (j * 16 + l16) * 64 + ((32 + quad * 8) ^ xr));
      sf[j] = __builtin_amdgcn_mfma_f32_16x16x32_bf16(aq0, bk0, sf[j], 0, 0, 0);
      sf[j] = __builtin_amdgcn_mfma_f32_16x16x32_bf16(aq1, bk1, sf[j], 0, 0, 0);
    }
    // logits = s/8 + w  (log_softmax lse cancels inside outer softmax)
    float lg[4][4];
#pragma unroll
    for (int j = 0; j < 4; ++j)
#pragma unroll
      for (int r = 0; r < 4; ++r) lg[j][r] = sf[j][r] * 0.125f + wc[j][r];

    float ps[4][4];
#pragma unroll
    for (int r = 0; r < 4; ++r) {
      float nm = fmaxf(fmaxf(lg[0][r], lg[1][r]), fmaxf(lg[2][r], lg[3][r]));
      nm = redmax16(nm);
      nm = fmaxf(nm, mrow[r]);
      float al = __expf(mrow[r] - nm);
      mrow[r] = nm;
      float rs = 0.f;
#pragma unroll
      for (int j = 0; j < 4; ++j) {
        ps[j][r] = __expf(lg[j][r] - nm);
        rs += ps[j][r];
      }
      rs = redsum16(rs);
      lrow[r] = lrow[r] * al + rs;
#pragma unroll
      for (int jd = 0; jd < 4; ++jd) o[jd][r] *= al;
    }
    // P: C-layout -> LDS [m][s^((m&7)<<3)] (wave-local: no barrier needed)
    u16* Pw = Ps[w];
#pragma unroll
    for (int j = 0; j < 4; ++j)
#pragma unroll
      for (int r = 0; r < 4; ++r) {
        int prow = quad * 4 + r;
        Pw[prow * 64 + ((j * 16 + l16) ^ ((prow & 7) << 3))] = f2bf(ps[j][r]);
      }
#pragma unroll
    for (int kk = 0; kk < 2; ++kk) {
      bf16x8 ap = *(const bf16x8*)(Pw + l16 * 64 + ((kk * 32 + quad * 8) ^ xr));
#pragma unroll
      for (int jd = 0; jd < 4; ++jd) {
        bf16x8 bv = *(const bf16x8*)(Vb + (jd * 16 + l16) * 64 + ((kk * 32 + quad * 8) ^ xr));
        o[jd] = __builtin_amdgcn_mfma_f32_16x16x32_bf16(ap, bv, o[jd], 0, 0, 0);
      }
    }
    if (st < 15) {
#pragma unroll
      for (int r = 0; r < 4; ++r)
#pragma unroll
        for (int j = 0; j < 4; ++j) wc[j][r] = wn[j][r];
    }
  }

  const int b = bh / 12, h = bh - (bh / 12) * 12;
  float il[4];
#pragma unroll
  for (int r = 0; r < 4; ++r) il[r] = __builtin_amdgcn_rcpf(lrow[r]);
#pragma unroll
  for (int jd = 0; jd < 4; ++jd)
#pragma unroll
    for (int r = 0; r < 4; ++r) {
      int row = b * 1024 + q0 + w * 16 + quad * 4 + r;
      int col = h * 64 + jd * 16 + l16;
      Oa[(size_t)row * 768 + col] = f2bf(o[jd][r] * il[r]);
    }
}

extern "C" void kernel_launch(void* const* d_in, const int* in_sizes, int n_in,
                              void* d_out, int out_size, void* d_ws, size_t ws_size,
                              hipStream_t stream) {
  const float* q  = (const float*)d_in[0];
  const float* aw = (const float*)d_in[1];
  const float* wq = (const float*)d_in[2];
  const float* wk = (const float*)d_in[3];
  const float* wv = (const float*)d_in[4];
  const float* wo = (const float*)d_in[5];
  const float* bo = (const float*)d_in[6];
  float* out = (float*)d_out;
  char* ws = (char*)d_ws;
  u16* X    = (u16*)(ws);
  u16* Wqkv = (u16*)(ws + 6291456);
  u16* Wob  = (u16*)(ws + 9830400);
  u16* QKV  = (u16*)(ws + 11010048);
  u16* Vt   = (u16*)(ws + 29884416);
  u16* Oa   = (u16*)(ws + 36175872);

  cast_all<<<5376, 256, 0, stream>>>(q, wq, wk, wv, wo, X, Wqkv, Wob);
  gemm_bt<0><<<dim3(18, 32), 256, 0, stream>>>(X, Wqkv, QKV, nullptr, nullptr);
  transpose_v<<<dim3(16, 48), 256, 0, stream>>>(QKV, Vt);
  attn_kernel<<<dim3(16, 48), 256, 0, stream>>>(QKV, Vt, aw, Oa);
  gemm_bt64<<<dim3(6, 64), 256, 0, stream>>>(Oa, Wob, out, bo);
}

// Round 7
// 364.811 us; speedup vs baseline: 1.0144x; 1.0144x over previous
//
#include <hip/hip_runtime.h>
#include <cstdint>
#include <cstddef>

typedef unsigned short u16;
typedef unsigned int u32;
typedef float f32x4 __attribute__((ext_vector_type(4)));
typedef short bf16x8 __attribute__((ext_vector_type(8)));

// Problem constants: B=4, N=S=1024, C=768, H=12, d=64
// ws layout (bytes):
//   X    @ 0         : 4096x768  bf16 (query cast)            6291456
//   Wqkv @ 6291456   : 2304x768  bf16 (Wq|Wk|Wv rows)         3538944
//   Wob  @ 9830400   : 768x768   bf16                         1179648
//   QKV  @ 11010048  : [3][4][12][1024][64] bf16 (t=2 slice now unused)
//   Vt   @ 29884416  : [4][12][64][1024] bf16                 6291456
//   Oa   @ 36175872  : [4096][768] bf16 (attn out, token-major) 6291456

#define GLOAD_LDS16(g, l)                                                        \
  __builtin_amdgcn_global_load_lds(                                              \
      (const __attribute__((address_space(1))) void*)(g),                        \
      (__attribute__((address_space(3))) void*)(l), 16, 0, 0)

__device__ __forceinline__ u16 f2bf(float f) {
  u32 u = __float_as_uint(f);
  u32 r = ((u >> 16) & 1u) + 0x7fffu;  // RNE
  return (u16)((u + r) >> 16);
}

__device__ __forceinline__ float redmax16(float v) {
  v = fmaxf(v, __shfl_xor(v, 8, 16));
  v = fmaxf(v, __shfl_xor(v, 4, 16));
  v = fmaxf(v, __shfl_xor(v, 2, 16));
  v = fmaxf(v, __shfl_xor(v, 1, 16));
  return v;
}
__device__ __forceinline__ float redsum16(float v) {
  v += __shfl_xor(v, 8, 16);
  v += __shfl_xor(v, 4, 16);
  v += __shfl_xor(v, 2, 16);
  v += __shfl_xor(v, 1, 16);
  return v;
}

// ---------------- cast all fp32 inputs to bf16 (flat ranges, 4 elems/thread) ---------
__global__ __launch_bounds__(256) void cast_all(
    const float* __restrict__ q, const float* __restrict__ wq, const float* __restrict__ wk,
    const float* __restrict__ wv, const float* __restrict__ wo,
    u16* __restrict__ X, u16* __restrict__ Wqkv, u16* __restrict__ Wob) {
  int id = blockIdx.x * 256 + threadIdx.x;  // quad index; grid covers exactly 1376256
  const float* src;
  u16* dst;
  if (id < 786432) {                     // query -> X
    src = q + (size_t)id * 4;       dst = X + (size_t)id * 4;
  } else if (id < 933888) {              // Wq -> Wqkv[0:768]
    int o = id - 786432;  src = wq + (size_t)o * 4; dst = Wqkv + (size_t)o * 4;
  } else if (id < 1081344) {             // Wk -> Wqkv[768:1536]
    int o = id - 933888;  src = wk + (size_t)o * 4; dst = Wqkv + 589824 + (size_t)o * 4;
  } else if (id < 1228800) {             // Wv -> Wqkv[1536:2304]
    int o = id - 1081344; src = wv + (size_t)o * 4; dst = Wqkv + 1179648 + (size_t)o * 4;
  } else {                               // Wo -> Wob
    int o = id - 1228800; src = wo + (size_t)o * 4; dst = Wob + (size_t)o * 4;
  }
  float4 v = *(const float4*)src;
  uint2 o2;
  o2.x = (u32)f2bf(v.x) | ((u32)f2bf(v.y) << 16);
  o2.y = (u32)f2bf(v.z) | ((u32)f2bf(v.w) << 16);
  *(uint2*)dst = o2;
}

// ---------------- QKV projection GEMM, C = X * Wqkv^T, 128x128 tiles -----------------
// m97 structure: linear [128][64] LDS per tile, global_load_lds 16B staging,
// XOR-swizzle as inverse-swizzled SOURCE + swizzled READ (rule #21).
// Q/K blocks (n0 < 1536): scatter-store bf16 into QKV [t][b][h][n][64].
// V blocks (n0 >= 1536): transpose in-block via LDS bounce, store Vt [b][h][64][n]
// directly (transpose_v kernel eliminated; QKV t=2 slice never written).
__global__ __launch_bounds__(256) void gemm_qkv(
    const u16* __restrict__ A, const u16* __restrict__ Bm,
    u16* __restrict__ Cq, u16* __restrict__ Vt) {
  constexpr int K = 768;
  __shared__ u16 S[2 * 128 * 64];  // As | Bs contiguous; re-used as 128x128 T for V
  u16* As = S;
  u16* Bs = S + 128 * 64;
  const int tid = threadIdx.x;
  const int w = tid >> 6, lane = tid & 63, quad = lane >> 4, l16 = lane & 15;
  const int m0 = blockIdx.y * 128, n0 = blockIdx.x * 128;
  const int wm = (w >> 1) * 64, wn = (w & 1) * 64;
  const int xr = (l16 & 7) << 3;  // read-side XOR (row&7 == l16&7 for 16-aligned rows)

  f32x4 acc[4][4];
#pragma unroll
  for (int i = 0; i < 4; ++i)
#pragma unroll
    for (int j = 0; j < 4; ++j)
#pragma unroll
      for (int r = 0; r < 4; ++r) acc[i][j][r] = 0.f;

  for (int kt = 0; kt < K; kt += 64) {
#pragma unroll
    for (int t = 0; t < 4; ++t) {
      int id = (t * 4 + w) * 64 + lane;          // 0..1023: lane's 16B within tile
      int row = id >> 3;
      int scol = ((id & 7) ^ (row & 7)) << 3;    // inverse-swizzled source column
      GLOAD_LDS16(A + (size_t)(m0 + row) * K + kt + scol, As + (t * 4 + w) * 512);
      GLOAD_LDS16(Bm + (size_t)(n0 + row) * K + kt + scol, Bs + (t * 4 + w) * 512);
    }
    __syncthreads();
#pragma unroll
    for (int kk = 0; kk < 2; ++kk) {
      bf16x8 af[4], bfr[4];
#pragma unroll
      for (int mi = 0; mi < 4; ++mi)
        af[mi] = *(const bf16x8*)(As + (wm + mi * 16 + l16) * 64 + ((kk * 32 + quad * 8) ^ xr));
#pragma unroll
      for (int ni = 0; ni < 4; ++ni)
        bfr[ni] = *(const bf16x8*)(Bs + (wn + ni * 16 + l16) * 64 + ((kk * 32 + quad * 8) ^ xr));
#pragma unroll
      for (int mi = 0; mi < 4; ++mi)
#pragma unroll
        for (int ni = 0; ni < 4; ++ni)
          acc[mi][ni] = __builtin_amdgcn_mfma_f32_16x16x32_bf16(af[mi], bfr[ni], acc[mi][ni], 0, 0, 0);
    }
    __syncthreads();
  }

  if (n0 >= 1536) {
    // ---- V epilogue: acc -> LDS (transposed, swizzled) -> coalesced Vt rows ----
    // T[row=dd_local][col=m_local], col swizzled by ((row&7)<<3). Safe to overlay
    // As/Bs: final loop barrier guarantees all LDS reads done.
    u16* T = S;  // 128x128 u16 = 32 KB
#pragma unroll
    for (int ni = 0; ni < 4; ++ni) {
#pragma unroll
      for (int mi = 0; mi < 4; ++mi) {
        int row = wn + ni * 16 + l16;           // dd_local 0..127
        int colb = wm + mi * 16 + quad * 4;     // m_local base, 4-aligned
        u16 p0 = f2bf(acc[mi][ni][0]), p1 = f2bf(acc[mi][ni][1]);
        u16 p2 = f2bf(acc[mi][ni][2]), p3 = f2bf(acc[mi][ni][3]);
        uint2 pk;
        pk.x = (u32)p0 | ((u32)p1 << 16);
        pk.y = (u32)p2 | ((u32)p3 << 16);
        // (colb^xrw)+r == (colb+r)^xrw since xrw is 8-aligned, colb 4-aligned, r<4
        *(uint2*)(T + row * 128 + (colb ^ ((row & 7) << 3))) = pk;
      }
    }
    __syncthreads();
    {
      int row = tid >> 1, half = tid & 1;       // row = dd_local
      int b = m0 >> 10;                          // block-uniform (128 | 1024)
      int tok0 = (m0 & 1023) + half * 64;
      int h = ((n0 - 1536) >> 6) + (row >> 6);   // two heads per block
      int dd = row & 63;
      u16* dst = Vt + ((size_t)(b * 12 + h) * 64 + dd) * 1024 + tok0;
      int xrw = (row & 7) << 3;
#pragma unroll
      for (int j = 0; j < 8; ++j)
        *(int4*)(dst + j * 8) = *(const int4*)(T + row * 128 + ((half * 64 + j * 8) ^ xrw));
    }
    return;
  }

  // ---- Q/K epilogue: scatter-store into QKV [t][b][h][n][64] ----
#pragma unroll
  for (int ni = 0; ni < 4; ++ni) {
    int cb = n0 + wn + ni * 16;  // 16-aligned; never straddles 768 or 64 boundaries
#pragma unroll
    for (int mi = 0; mi < 4; ++mi) {
#pragma unroll
      for (int r = 0; r < 4; ++r) {
        int m = m0 + wm + mi * 16 + quad * 4 + r;  // C/D row = quad*4+reg
        int t = cb / 768;
        int c = cb - t * 768;
        int h = c >> 6, dd = (c & 63) + l16;       // C/D col = lane&15
        int b = m >> 10, ntok = m & 1023;
        Cq[(size_t)((t * 4 + b) * 12 + h) * 65536 + (size_t)ntok * 64 + dd] = f2bf(acc[mi][ni][r]);
      }
    }
  }
}

// ---------------- 64x128 GEMM for the output projection -----------------------------
// M=4096, N=768, K=768. grid (6, 64) = 384 blocks. Same staging + swizzle discipline.
__global__ __launch_bounds__(256) void gemm_bt64(
    const u16* __restrict__ A, const u16* __restrict__ Bm,
    float* __restrict__ Cf, const float* __restrict__ bias) {
  constexpr int K = 768;
  __shared__ u16 As[64 * 64];    // 8 KB
  __shared__ u16 Bs[128 * 64];   // 16 KB
  const int tid = threadIdx.x;
  const int w = tid >> 6, lane = tid & 63, quad = lane >> 4, l16 = lane & 15;
  const int m0 = blockIdx.y * 64, n0 = blockIdx.x * 128;
  const int wm = (w >> 1) * 32, wn = (w & 1) * 64;
  const int xr = (l16 & 7) << 3;

  f32x4 acc[2][4];
#pragma unroll
  for (int i = 0; i < 2; ++i)
#pragma unroll
    for (int j = 0; j < 4; ++j)
#pragma unroll
      for (int r = 0; r < 4; ++r) acc[i][j][r] = 0.f;

  for (int kt = 0; kt < K; kt += 64) {
#pragma unroll
    for (int t = 0; t < 4; ++t) {
      int id = (t * 4 + w) * 64 + lane;
      int row = id >> 3, scol = ((id & 7) ^ (row & 7)) << 3;
      GLOAD_LDS16(Bm + (size_t)(n0 + row) * K + kt + scol, Bs + (t * 4 + w) * 512);
      if (t < 2) {  // A tile: 8 chunks (rows 0..63)
        GLOAD_LDS16(A + (size_t)(m0 + row) * K + kt + scol, As + (t * 4 + w) * 512);
      }
    }
    __syncthreads();
#pragma unroll
    for (int kk = 0; kk < 2; ++kk) {
      bf16x8 af[2], bfr[4];
#pragma unroll
      for (int mi = 0; mi < 2; ++mi)
        af[mi] = *(const bf16x8*)(As + (wm + mi * 16 + l16) * 64 + ((kk * 32 + quad * 8) ^ xr));
#pragma unroll
      for (int ni = 0; ni < 4; ++ni)
        bfr[ni] = *(const bf16x8*)(Bs + (wn + ni * 16 + l16) * 64 + ((kk * 32 + quad * 8) ^ xr));
#pragma unroll
      for (int mi = 0; mi < 2; ++mi)
#pragma unroll
        for (int ni = 0; ni < 4; ++ni)
          acc[mi][ni] = __builtin_amdgcn_mfma_f32_16x16x32_bf16(af[mi], bfr[ni], acc[mi][ni], 0, 0, 0);
    }
    __syncthreads();
  }

#pragma unroll
  for (int ni = 0; ni < 4; ++ni) {
    int n = n0 + wn + ni * 16 + l16;
#pragma unroll
    for (int mi = 0; mi < 2; ++mi) {
#pragma unroll
      for (int r = 0; r < 4; ++r) {
        int m = m0 + wm + mi * 16 + quad * 4 + r;
        Cf[(size_t)m * 768 + n] = acc[mi][ni][r] + bias[n];
      }
    }
  }
}

// ---------------- fused attention: softmax(QK^T/8 + W) V, online softmax ------------
// grid (16 q-tiles of 64, 48 bh); 256 threads = 4 waves, 16 q-rows per wave.
// K/V double-buffered via global_load_lds prefetched one tile ahead; W bias
// prefetched one tile ahead into registers. LDS = 40960 B -> 4 blocks/CU.
__global__ __launch_bounds__(256, 4) void attn_kernel(
    const u16* __restrict__ QKV, const u16* __restrict__ Vt,
    const float* __restrict__ W, u16* __restrict__ Oa) {
  __shared__ u16 Ks2[2][64 * 64];  // [buf][s_local][dd], XOR-swizzled storage
  __shared__ u16 Vs2[2][64 * 64];  // [buf][dd][s_local], XOR-swizzled storage
  __shared__ u16 Ps[4][16 * 64];   // per-wave P tile [m][s_local], XOR-swizzled
  const int tid = threadIdx.x;
  const int w = tid >> 6, lane = tid & 63, quad = lane >> 4, l16 = lane & 15;
  const int bh = blockIdx.y, q0 = blockIdx.x * 64;
  const u16* Qh = QKV + (size_t)bh * 65536;
  const u16* Kh = QKV + (size_t)(48 + bh) * 65536;
  const u16* Vth = Vt + (size_t)bh * 65536;
  const float* Wp = W + (size_t)bh * 1048576 + (size_t)(q0 + w * 16 + quad * 4) * 1024 + l16;
  const int xr = (l16 & 7) << 3;

  // Q fragments for this wave's 16 rows (A-layout: m=lane&15, k=quad*8+j)
  bf16x8 aq0, aq1;
  {
    int qrow = q0 + w * 16 + l16;
    aq0 = *(const bf16x8*)(Qh + (size_t)qrow * 64 + quad * 8);
    aq1 = *(const bf16x8*)(Qh + (size_t)qrow * 64 + 32 + quad * 8);
  }

  // staging geometry: 8KB tile = 8 x 1KB chunks; chunk = c*4+w; lane covers 16B
  const int sid0 = (0 * 4 + w) * 64 + lane;
  const int sid1 = (1 * 4 + w) * 64 + lane;
  const int r0 = sid0 >> 3, sl0 = ((sid0 & 7) ^ (r0 & 7)) << 3;
  const int r1 = sid1 >> 3, sl1 = ((sid1 & 7) ^ (r1 & 7)) << 3;

  // prologue: stage tile 0 into buf 0; W tile 0 into regs
  GLOAD_LDS16(Kh + (size_t)r0 * 64 + sl0, &Ks2[0][(0 * 4 + w) * 512]);
  GLOAD_LDS16(Kh + (size_t)r1 * 64 + sl1, &Ks2[0][(1 * 4 + w) * 512]);
  GLOAD_LDS16(Vth + (size_t)r0 * 1024 + sl0, &Vs2[0][(0 * 4 + w) * 512]);
  GLOAD_LDS16(Vth + (size_t)r1 * 1024 + sl1, &Vs2[0][(1 * 4 + w) * 512]);
  float wc[4][4];
#pragma unroll
  for (int r = 0; r < 4; ++r)
#pragma unroll
    for (int j = 0; j < 4; ++j) wc[j][r] = Wp[(size_t)r * 1024 + j * 16];

  f32x4 o[4];
  float mrow[4], lrow[4];
#pragma unroll
  for (int j = 0; j < 4; ++j)
#pragma unroll
    for (int r = 0; r < 4; ++r) o[j][r] = 0.f;
#pragma unroll
  for (int r = 0; r < 4; ++r) { mrow[r] = -1e30f; lrow[r] = 0.f; }

  for (int st = 0; st < 16; ++st) {
    const int cur = st & 1;
    __syncthreads();  // drains staged tile(st); all waves done reading buf[cur^1]

    // prefetch tile st+1 into buf[cur^1]; skip on last iter (no dangling
    // in-flight LDS DMA at endpgm, no wasted HBM traffic)
    float wn[4][4];
    if (st < 15) {
      const int sn = (st + 1) * 64;
      GLOAD_LDS16(Kh + (size_t)(sn + r0) * 64 + sl0, &Ks2[cur ^ 1][(0 * 4 + w) * 512]);
      GLOAD_LDS16(Kh + (size_t)(sn + r1) * 64 + sl1, &Ks2[cur ^ 1][(1 * 4 + w) * 512]);
      GLOAD_LDS16(Vth + (size_t)r0 * 1024 + sn + sl0, &Vs2[cur ^ 1][(0 * 4 + w) * 512]);
      GLOAD_LDS16(Vth + (size_t)r1 * 1024 + sn + sl1, &Vs2[cur ^ 1][(1 * 4 + w) * 512]);
#pragma unroll
      for (int r = 0; r < 4; ++r)
#pragma unroll
        for (int j = 0; j < 4; ++j) wn[j][r] = Wp[(size_t)r * 1024 + sn + j * 16];
    }

    const u16* Kb = Ks2[cur];
    const u16* Vb = Vs2[cur];

    // scores: S[m=q-row][n=s-col]
    f32x4 sf[4];
#pragma unroll
    for (int j = 0; j < 4; ++j) {
#pragma unroll
      for (int r = 0; r < 4; ++r) sf[j][r] = 0.f;
      bf16x8 bk0 = *(const bf16x8*)(Kb + (j * 16 + l16) * 64 + ((quad * 8) ^ xr));
      bf16x8 bk1 = *(const bf16x8*)(Kb + (j * 16 + l16) * 64 + ((32 + quad * 8) ^ xr));
      sf[j] = __builtin_amdgcn_mfma_f32_16x16x32_bf16(aq0, bk0, sf[j], 0, 0, 0);
      sf[j] = __builtin_amdgcn_mfma_f32_16x16x32_bf16(aq1, bk1, sf[j], 0, 0, 0);
    }
    // logits = s/8 + w  (log_softmax lse cancels inside outer softmax)
    float lg[4][4];
#pragma unroll
    for (int j = 0; j < 4; ++j)
#pragma unroll
      for (int r = 0; r < 4; ++r) lg[j][r] = sf[j][r] * 0.125f + wc[j][r];

    float ps[4][4];
#pragma unroll
    for (int r = 0; r < 4; ++r) {
      float nm = fmaxf(fmaxf(lg[0][r], lg[1][r]), fmaxf(lg[2][r], lg[3][r]));
      nm = redmax16(nm);
      nm = fmaxf(nm, mrow[r]);
      float al = __expf(mrow[r] - nm);
      mrow[r] = nm;
      float rs = 0.f;
#pragma unroll
      for (int j = 0; j < 4; ++j) {
        ps[j][r] = __expf(lg[j][r] - nm);
        rs += ps[j][r];
      }
      rs = redsum16(rs);
      lrow[r] = lrow[r] * al + rs;
#pragma unroll
      for (int jd = 0; jd < 4; ++jd) o[jd][r] *= al;
    }
    // P: C-layout -> LDS [m][s^((m&7)<<3)] (wave-local: no barrier needed)
    u16* Pw = Ps[w];
#pragma unroll
    for (int j = 0; j < 4; ++j)
#pragma unroll
      for (int r = 0; r < 4; ++r) {
        int prow = quad * 4 + r;
        Pw[prow * 64 + ((j * 16 + l16) ^ ((prow & 7) << 3))] = f2bf(ps[j][r]);
      }
#pragma unroll
    for (int kk = 0; kk < 2; ++kk) {
      bf16x8 ap = *(const bf16x8*)(Pw + l16 * 64 + ((kk * 32 + quad * 8) ^ xr));
#pragma unroll
      for (int jd = 0; jd < 4; ++jd) {
        bf16x8 bv = *(const bf16x8*)(Vb + (jd * 16 + l16) * 64 + ((kk * 32 + quad * 8) ^ xr));
        o[jd] = __builtin_amdgcn_mfma_f32_16x16x32_bf16(ap, bv, o[jd], 0, 0, 0);
      }
    }
    if (st < 15) {
#pragma unroll
      for (int r = 0; r < 4; ++r)
#pragma unroll
        for (int j = 0; j < 4; ++j) wc[j][r] = wn[j][r];
    }
  }

  const int b = bh / 12, h = bh - (bh / 12) * 12;
  float il[4];
#pragma unroll
  for (int r = 0; r < 4; ++r) il[r] = __builtin_amdgcn_rcpf(lrow[r]);
#pragma unroll
  for (int jd = 0; jd < 4; ++jd)
#pragma unroll
    for (int r = 0; r < 4; ++r) {
      int row = b * 1024 + q0 + w * 16 + quad * 4 + r;
      int col = h * 64 + jd * 16 + l16;
      Oa[(size_t)row * 768 + col] = f2bf(o[jd][r] * il[r]);
    }
}

extern "C" void kernel_launch(void* const* d_in, const int* in_sizes, int n_in,
                              void* d_out, int out_size, void* d_ws, size_t ws_size,
                              hipStream_t stream) {
  const float* q  = (const float*)d_in[0];
  const float* aw = (const float*)d_in[1];
  const float* wq = (const float*)d_in[2];
  const float* wk = (const float*)d_in[3];
  const float* wv = (const float*)d_in[4];
  const float* wo = (const float*)d_in[5];
  const float* bo = (const float*)d_in[6];
  float* out = (float*)d_out;
  char* ws = (char*)d_ws;
  u16* X    = (u16*)(ws);
  u16* Wqkv = (u16*)(ws + 6291456);
  u16* Wob  = (u16*)(ws + 9830400);
  u16* QKV  = (u16*)(ws + 11010048);
  u16* Vt   = (u16*)(ws + 29884416);
  u16* Oa   = (u16*)(ws + 36175872);

  cast_all<<<5376, 256, 0, stream>>>(q, wq, wk, wv, wo, X, Wqkv, Wob);
  gemm_qkv<<<dim3(18, 32), 256, 0, stream>>>(X, Wqkv, QKV, Vt);
  attn_kernel<<<dim3(16, 48), 256, 0, stream>>>(QKV, Vt, aw, Oa);
  gemm_bt64<<<dim3(6, 64), 256, 0, stream>>>(Oa, Wob, out, bo);
}